// Round 6
// baseline (26.589 us; speedup 1.0000x reference)
//
#include <hip/hip_runtime.h>
#include <math.h>

// PositionalEncoding: out = x * sqrt(512) + pe, pe interleaved sin/cos of
// positions[b,s] * div_term[i], div_term[i] = 10000^(-i/256), d_model = 512.
//
// Memory-bound elementwise op (~134 MB traffic). 8-deep burst variant:
// each wave covers 4 full rows (512 consecutive f4); each thread issues
// 8 independent 16B NT loads up front (128 B/lane in flight — copy-ubench
// depth), computes all trig, then 8 NT stores.
//   - ONE v_exp per thread: dt set shared by all 4 rows; cols lane+64 use
//     dt*0.01 exactly (10000^(-128/256) = 1/100).
//   - positions via 4 scalar loads (wave-uniform rows).

#define D_MODEL 512

typedef float f32x4 __attribute__((ext_vector_type(4)));

__global__ __launch_bounds__(256) void pe_kernel(
    const f32x4* __restrict__ x,
    const int*   __restrict__ positions,
    f32x4*       __restrict__ out)
{
    const float SQRT_D   = 22.627416997969522f;       // sqrt(512)
    const float C2       = -0.05190512364928082f;     // -log2(10000)/256
    const float INV2PI   = 0.15915494309189535f;      // 1/(2*pi)
    const float DT_RATIO = 0.9646616199111993f;       // 10000^(-1/256)

    int t    = blockIdx.x * blockDim.x + threadIdx.x;
    int wid  = __builtin_amdgcn_readfirstlane(t >> 6); // wave id -> SGPR
    int lane = t & 63;
    int r0i  = wid * 4;                                // first row of the quad
    long base = (long)r0i * 128 + lane;                // f4 index

    // 8 independent loads, issued back-to-back (128 B/lane in flight)
    f32x4 v0 = __builtin_nontemporal_load(&x[base]);        // row0, col lane
    f32x4 v1 = __builtin_nontemporal_load(&x[base + 64]);   // row0, col lane+64
    f32x4 v2 = __builtin_nontemporal_load(&x[base + 128]);  // row1
    f32x4 v3 = __builtin_nontemporal_load(&x[base + 192]);
    f32x4 v4 = __builtin_nontemporal_load(&x[base + 256]);  // row2
    f32x4 v5 = __builtin_nontemporal_load(&x[base + 320]);
    f32x4 v6 = __builtin_nontemporal_load(&x[base + 384]);  // row3
    f32x4 v7 = __builtin_nontemporal_load(&x[base + 448]);

    float prA = (float)positions[r0i]     * INV2PI;    // scalar, broadcast
    float prB = (float)positions[r0i + 1] * INV2PI;
    float prC = (float)positions[r0i + 2] * INV2PI;
    float prD = (float)positions[r0i + 3] * INV2PI;

    // div_terms for f4-col lane: pairs (2*lane, 2*lane+1); col lane+64 -> *0.01
    float dt0 = __builtin_amdgcn_exp2f((float)(2 * lane) * C2);
    float dt1 = dt0 * DT_RATIO;
    float dt2 = dt0 * 0.01f;
    float dt3 = dt1 * 0.01f;

#define RED(p, d) ({ float _r = (p) * (d); _r - floorf(_r); })
#define PE4(o, v, p, dA, dB) do {                                   \
        float _a0 = RED(p, dA), _a1 = RED(p, dB);                   \
        o.x = v.x * SQRT_D + __builtin_amdgcn_sinf(_a0);            \
        o.y = v.y * SQRT_D + __builtin_amdgcn_cosf(_a0);            \
        o.z = v.z * SQRT_D + __builtin_amdgcn_sinf(_a1);            \
        o.w = v.w * SQRT_D + __builtin_amdgcn_cosf(_a1);            \
    } while (0)

    f32x4 o0, o1, o2, o3, o4, o5, o6, o7;
    PE4(o0, v0, prA, dt0, dt1);
    PE4(o1, v1, prA, dt2, dt3);
    PE4(o2, v2, prB, dt0, dt1);
    PE4(o3, v3, prB, dt2, dt3);
    PE4(o4, v4, prC, dt0, dt1);
    PE4(o5, v5, prC, dt2, dt3);
    PE4(o6, v6, prD, dt0, dt1);
    PE4(o7, v7, prD, dt2, dt3);
#undef PE4
#undef RED

    __builtin_nontemporal_store(o0, &out[base]);
    __builtin_nontemporal_store(o1, &out[base + 64]);
    __builtin_nontemporal_store(o2, &out[base + 128]);
    __builtin_nontemporal_store(o3, &out[base + 192]);
    __builtin_nontemporal_store(o4, &out[base + 256]);
    __builtin_nontemporal_store(o5, &out[base + 320]);
    __builtin_nontemporal_store(o6, &out[base + 384]);
    __builtin_nontemporal_store(o7, &out[base + 448]);
}

extern "C" void kernel_launch(void* const* d_in, const int* in_sizes, int n_in,
                              void* d_out, int out_size, void* d_ws, size_t ws_size,
                              hipStream_t stream) {
    const float* x   = (const float*)d_in[0];
    const int*   pos = (const int*)d_in[1];
    float*       out = (float*)d_out;

    int nrows = out_size / D_MODEL;        // 32768 rows
    int block = 256;
    int grid  = nrows / 16;                // 4 rows/wave, 4 waves/block -> 2048
    pe_kernel<<<grid, block, 0, stream>>>(
        (const f32x4*)x, pos, (f32x4*)out);
}